// Round 5
// baseline (149.579 us; speedup 1.0000x reference)
//
#include <hip/hip_runtime.h>

// n = 8192 points, d = 512, fp32 in, scalar fp32 out.
// Pipeline:
//   (1) fp32 -> fp8 e4m3 convert (+ zero-init packed argmax keys)
//   (2) triangular fused fp8-MFMA GEMM (16x16x32_fp8_fp8, bf16-rate but half
//       the LDS/L2 bytes): 128x128 tiles, BK=32 (32 B/row), 4-buffer LDS
//       (32 KB), depth-2 counted-vmcnt pipeline, 5 blocks/CU. Dual row/col
//       argmax per tile via deterministic u64 atomicMax of
//       (monotone(value)<<32 | ~index) -> exact first-occurrence ties.
//   (3) per-row ||x - x[I] + 1e-6||_2 -> log   (full fp32)
//   (4) deterministic mean reduce.

#define NPTS 8192
#define DIM  512
#define BM   128
#define BN   128
#define NTIL 64
#define NBLK (NTIL * (NTIL + 1) / 2)   // 2080 (= 8*260, XCD-divisible)

typedef float f32x4 __attribute__((ext_vector_type(4)));

// f32 -> OCP e4m3fn, round-to-nearest-even, denormals handled, FTZ below
// 2^-10. Values here are N(0,1): no clamping in practice (max 448).
__device__ __forceinline__ unsigned char f32_to_e4m3(float f) {
  unsigned u = __builtin_bit_cast(unsigned, f);
  unsigned s = (u >> 24) & 0x80u;
  unsigned a = u & 0x7FFFFFFFu;
  float af = __builtin_bit_cast(float, a);
  if (af < 0.015625f) {                    // below min normal 2^-6
    int m = (int)rintf(af * 512.0f);       // RNE; 8 naturally -> 2^-6 normal
    return (unsigned char)(s | (unsigned)m);
  }
  unsigned u2 = a + 0x0007FFFFu + ((a >> 20) & 1u);  // RNE to 3-bit mantissa
  int e = (int)(u2 >> 23) - 127 + 7;
  unsigned m = (u2 >> 20) & 7u;
  if (e > 15) return (unsigned char)(s | 0x7Eu);     // clamp to 448
  return (unsigned char)(s | ((unsigned)e << 3) | m);
}

// Order-preserving f32 -> u32.
__device__ __forceinline__ unsigned int mono_f32(float f) {
  unsigned int u = __builtin_bit_cast(unsigned int, f);
  return (u & 0x80000000u) ? ~u : (u | 0x80000000u);
}

__global__ void cvt_fp8_kernel(const float* __restrict__ x,
                               unsigned char* __restrict__ xq,
                               unsigned long long* __restrict__ nn64) {
  int i = blockIdx.x * blockDim.x + threadIdx.x;     // 8 elems per thread
  const float4* xp = reinterpret_cast<const float4*>(x) + 2 * (size_t)i;
  float4 v0 = xp[0], v1 = xp[1];
  unsigned long long w =
      (unsigned long long)f32_to_e4m3(v0.x) |
      ((unsigned long long)f32_to_e4m3(v0.y) << 8) |
      ((unsigned long long)f32_to_e4m3(v0.z) << 16) |
      ((unsigned long long)f32_to_e4m3(v0.w) << 24) |
      ((unsigned long long)f32_to_e4m3(v1.x) << 32) |
      ((unsigned long long)f32_to_e4m3(v1.y) << 40) |
      ((unsigned long long)f32_to_e4m3(v1.z) << 48) |
      ((unsigned long long)f32_to_e4m3(v1.w) << 56);
  reinterpret_cast<unsigned long long*>(xq)[i] = w;
  if (i < NPTS) nn64[i] = 0ull;
}

__device__ __forceinline__ void gload_lds16(const unsigned char* g,
                                            unsigned char* l) {
  __builtin_amdgcn_global_load_lds(
      (__attribute__((address_space(1))) const void*)g,
      (__attribute__((address_space(3))) void*)l, 16, 0, 0);
}

__device__ __forceinline__ unsigned long long kmax(unsigned long long a,
                                                   unsigned long long b) {
  return a > b ? a : b;
}

// Triangular fused fp8 GEMM + dual argmax.
// grid = NBLK, block = 256 (4 waves, 2x2 grid of 64x64 sub-tiles).
// LDS: 4 buffers x (A 4KB + B 4KB) = 32 KB -> 5 blocks/CU.
__global__ __launch_bounds__(256, 5) void tri_gemm_kernel(
    const unsigned char* __restrict__ xq,
    unsigned long long* __restrict__ nn64) {
  __shared__ unsigned char lds[4][8192];

  // XCD-bijective swizzle (2080 = 8*260), then b -> (ti >= tj).
  const int orig = (int)blockIdx.x;
  int b = (orig & 7) * (NBLK >> 3) + (orig >> 3);
  int ti = (int)((sqrtf(8.0f * (float)b + 1.0f) - 1.0f) * 0.5f);
  while ((ti + 1) * (ti + 2) / 2 <= b) ++ti;
  while (ti * (ti + 1) / 2 > b) --ti;
  const int tj = b - ti * (ti + 1) / 2;

  const int tid  = (int)threadIdx.x;
  const int wid  = tid >> 6;
  const int lane = tid & 63;
  const int wr   = wid >> 1;      // 0..1
  const int wc   = wid & 1;       // 0..1
  const int l15  = lane & 15;
  const int l16  = lane >> 4;     // 0..3 (8-byte k-chunk index)
  const int arow0 = ti * BM;
  const int bcol0 = tj * BN;

  // Staging: 256 16B-chunks per operand per K-step; 1 A + 1 B chunk/thread.
  // Source-side swizzle: slot sl within row stores global chunk
  // sl ^ ((row>>2)&1)  (1-bit involution -> <=2-way reads, free).
  const int srow = tid >> 1;
  const int sg   = (tid & 1) ^ ((srow >> 2) & 1);
  const unsigned char* gA0 = xq + (size_t)(arow0 + srow) * DIM + (sg << 4);
  const unsigned char* gB0 = xq + (size_t)(bcol0 + srow) * DIM + (sg << 4);

#define STAGE(bufi, kt) do {                                                 \
    gload_lds16(gA0 + (kt) * 32, &lds[bufi][wid << 10]);                     \
    gload_lds16(gB0 + (kt) * 32, &lds[bufi][4096 + (wid << 10)]);            \
  } while (0)

  // Fragment read offsets: lane wants row r, k-bytes l16*8..+8 of the 32B
  // row; stored slot = (l16>>1) ^ ((r>>2)&1), byte-in-slot = (l16&1)*8.
  const int sb    = (l15 >> 2) & 1;
  const int kpart = ((((l16 >> 1) ^ sb) << 4) | ((l16 & 1) << 3));
  int aoff[4], boff[4];
#pragma unroll
  for (int mi = 0; mi < 4; ++mi)
    aoff[mi] = (wr * 64 + mi * 16 + l15) * 32 + kpart;
#pragma unroll
  for (int ni = 0; ni < 4; ++ni)
    boff[ni] = 4096 + (wc * 64 + ni * 16 + l15) * 32 + kpart;

  f32x4 acc[4][4];
#pragma unroll
  for (int mi = 0; mi < 4; ++mi)
#pragma unroll
    for (int ni = 0; ni < 4; ++ni)
      acc[mi][ni] = (f32x4){0.f, 0.f, 0.f, 0.f};

  // Prologue: 2 K-steps in flight (depth-2).
  STAGE(0, 0);
  STAGE(1, 1);

  for (int u = 0; u < 16; ++u) {
    const int cur = u & 3;
    if (u + 2 < 16) {
      STAGE((u + 2) & 3, u + 2);
      asm volatile("s_waitcnt vmcnt(4)" ::: "memory");  // step u's 2 done
    } else if (u + 2 == 16) {
      asm volatile("s_waitcnt vmcnt(2)" ::: "memory");
    } else {
      asm volatile("s_waitcnt vmcnt(0)" ::: "memory");
    }
    asm volatile("s_barrier" ::: "memory");             // buf[cur] published

    long a64[4], b64[4];
#pragma unroll
    for (int mi = 0; mi < 4; ++mi)
      a64[mi] = *reinterpret_cast<const long*>(&lds[cur][aoff[mi]]);
#pragma unroll
    for (int ni = 0; ni < 4; ++ni)
      b64[ni] = *reinterpret_cast<const long*>(&lds[cur][boff[ni]]);
    __builtin_amdgcn_s_setprio(1);
#pragma unroll
    for (int mi = 0; mi < 4; ++mi)
#pragma unroll
      for (int ni = 0; ni < 4; ++ni)
        acc[mi][ni] = __builtin_amdgcn_mfma_f32_16x16x32_fp8_fp8(
            a64[mi], b64[ni], acc[mi][ni], 0, 0, 0);
    __builtin_amdgcn_s_setprio(0);

    asm volatile("s_barrier" ::: "memory");   // reads of buf[cur] done
  }
#undef STAGE

  // ---- Epilogue: dual argmax. C/D layout: col=lane&15, row=(lane>>4)*4+reg.
  // Key = mono(v)<<32 | ~idx  (atomicMax => exact first-occurrence ties).

  // Row side: per output row, max over this wave's 64 columns.
#pragma unroll
  for (int mi = 0; mi < 4; ++mi)
#pragma unroll
    for (int j = 0; j < 4; ++j) {
      const int gi = arow0 + wr * 64 + mi * 16 + l16 * 4 + j;
      unsigned long long key = 0ull;
#pragma unroll
      for (int ni = 0; ni < 4; ++ni) {
        const int gj = bcol0 + wc * 64 + ni * 16 + l15;
        if (gi != gj) {
          unsigned long long k =
              ((unsigned long long)mono_f32(acc[mi][ni][j]) << 32) |
              (unsigned int)(~gj);
          key = kmax(key, k);
        }
      }
#pragma unroll
      for (int m = 1; m < 16; m <<= 1)
        key = kmax(key, __shfl_xor(key, m));
      if (l15 == 0) atomicMax(&nn64[gi], key);
    }

  // Col side (symmetry): per output col, max over this wave's 64 rows.
#pragma unroll
  for (int ni = 0; ni < 4; ++ni) {
    const int gj = bcol0 + wc * 64 + ni * 16 + l15;
    unsigned long long key = 0ull;
#pragma unroll
    for (int mi = 0; mi < 4; ++mi)
#pragma unroll
      for (int j = 0; j < 4; ++j) {
        const int gi = arow0 + wr * 64 + mi * 16 + l16 * 4 + j;
        if (gi != gj) {
          unsigned long long k =
              ((unsigned long long)mono_f32(acc[mi][ni][j]) << 32) |
              (unsigned int)(~gi);
          key = kmax(key, k);
        }
      }
#pragma unroll
    for (int m = 16; m < 64; m <<= 1)
      key = kmax(key, __shfl_xor(key, m));
    if (l16 == 0) atomicMax(&nn64[gj], key);
  }
}

// rho_r = ||x_r - x_{nn(r)} + 1e-6||_2 ; logs[r] = log(rho + 1e-8).
__global__ void dist_log_kernel(const float* __restrict__ x,
                                const unsigned long long* __restrict__ nn64,
                                float* __restrict__ logs) {
  const int row  = blockIdx.x * 4 + ((int)threadIdx.x >> 6);
  const int lane = (int)threadIdx.x & 63;
  const int nn   = (int)(~(unsigned int)(nn64[row] & 0xFFFFFFFFull)) & (NPTS - 1);
  const float4* xr = reinterpret_cast<const float4*>(x + (size_t)row * DIM);
  const float4* xn = reinterpret_cast<const float4*>(x + (size_t)nn  * DIM);
  float s = 0.f;
#pragma unroll
  for (int i = 0; i < 2; ++i) {
    float4 a = xr[lane + i * 64];
    float4 b = xn[lane + i * 64];
    float d0 = a.x - b.x + 1e-6f;
    float d1 = a.y - b.y + 1e-6f;
    float d2 = a.z - b.z + 1e-6f;
    float d3 = a.w - b.w + 1e-6f;
    s += d0 * d0 + d1 * d1 + d2 * d2 + d3 * d3;
  }
#pragma unroll
  for (int m = 32; m >= 1; m >>= 1) s += __shfl_xor(s, m);
  if (lane == 0) logs[row] = logf(sqrtf(s) + 1e-8f);
}

// Deterministic mean: 1024 threads x 8 sequential adds + LDS tree.
__global__ void final_reduce_kernel(const float* __restrict__ logs,
                                    float* __restrict__ out) {
  __shared__ float sm[1024];
  const int t = (int)threadIdx.x;
  float s = 0.f;
#pragma unroll
  for (int i = 0; i < 8; ++i) s += logs[t * 8 + i];
  sm[t] = s;
  __syncthreads();
  for (int k = 512; k > 0; k >>= 1) {
    if (t < k) sm[t] += sm[t + k];
    __syncthreads();
  }
  if (t == 0) out[0] = -(sm[0] / (float)NPTS);
}

extern "C" void kernel_launch(void* const* d_in, const int* in_sizes, int n_in,
                              void* d_out, int out_size, void* d_ws, size_t ws_size,
                              hipStream_t stream) {
  const float* x = (const float*)d_in[0];
  float* out = (float*)d_out;
  char* ws = (char*)d_ws;

  // Workspace layout (bytes):
  unsigned char*      xq   = (unsigned char*)(ws);                // 4 MB
  unsigned long long* nn64 = (unsigned long long*)(ws + 4194304); // 64 KB
  float*              logs = (float*)(ws + 4259840);              // 32 KB

  cvt_fp8_kernel<<<(NPTS * DIM / 8) / 256, 256, 0, stream>>>(x, xq, nn64);

  tri_gemm_kernel<<<NBLK, 256, 0, stream>>>(xq, nn64);

  dist_log_kernel<<<NPTS / 4, 256, 0, stream>>>(x, nn64, logs);

  final_reduce_kernel<<<1, 1024, 0, stream>>>(logs, out);
}

// Round 6
// 80.204 us; speedup vs baseline: 1.8650x; 1.8650x over previous
//
#include <hip/hip_runtime.h>

// n = 8192 points, d = 512, fp32 in, scalar fp32 out.
// Pipeline:
//   (1) fp32 -> fp8 e4m3 convert (+ zero-init packed argmax keys)
//   (2) triangular fused fp8-MFMA GEMM (16x16x32_fp8_fp8): 128x128 tiles,
//       BK=64 (64 B/row, 16B slot-rotation layout -> b128 frag reads, ~2-way
//       banks), 3x16KB LDS buffers, depth-2 counted-vmcnt pipeline,
//       3 blocks/CU (no spill). Dual row/col argmax per tile via
//       deterministic u64 atomicMax of (monotone(value)<<32 | ~index).
//   (3) per-row ||x - x[I] + 1e-6||_2 -> log   (full fp32)
//   (4) deterministic mean reduce.

#define NPTS 8192
#define DIM  512
#define BM   128
#define BN   128
#define NTIL 64
#define NBLK (NTIL * (NTIL + 1) / 2)   // 2080 (= 8*260, XCD-divisible)
#define KT_N 8                          // 512 / 64

typedef float f32x4 __attribute__((ext_vector_type(4)));
typedef long  lx2   __attribute__((ext_vector_type(2)));   // 16 B

// f32 -> OCP e4m3fn, round-to-nearest-even; N(0,1) data never clamps.
__device__ __forceinline__ unsigned char f32_to_e4m3(float f) {
  unsigned u = __builtin_bit_cast(unsigned, f);
  unsigned s = (u >> 24) & 0x80u;
  unsigned a = u & 0x7FFFFFFFu;
  float af = __builtin_bit_cast(float, a);
  if (af < 0.015625f) {                    // below min normal 2^-6
    int m = (int)rintf(af * 512.0f);       // RNE; 8 naturally -> 2^-6 normal
    return (unsigned char)(s | (unsigned)m);
  }
  unsigned u2 = a + 0x0007FFFFu + ((a >> 20) & 1u);  // RNE to 3-bit mantissa
  int e = (int)(u2 >> 23) - 127 + 7;
  unsigned m = (u2 >> 20) & 7u;
  if (e > 15) return (unsigned char)(s | 0x7Eu);     // clamp to 448
  return (unsigned char)(s | ((unsigned)e << 3) | m);
}

// Order-preserving f32 -> u32.
__device__ __forceinline__ unsigned int mono_f32(float f) {
  unsigned int u = __builtin_bit_cast(unsigned int, f);
  return (u & 0x80000000u) ? ~u : (u | 0x80000000u);
}

__global__ void cvt_fp8_kernel(const float* __restrict__ x,
                               unsigned char* __restrict__ xq,
                               unsigned long long* __restrict__ nn64) {
  int i = blockIdx.x * blockDim.x + threadIdx.x;     // 8 elems per thread
  const float4* xp = reinterpret_cast<const float4*>(x) + 2 * (size_t)i;
  float4 v0 = xp[0], v1 = xp[1];
  unsigned long long w =
      (unsigned long long)f32_to_e4m3(v0.x) |
      ((unsigned long long)f32_to_e4m3(v0.y) << 8) |
      ((unsigned long long)f32_to_e4m3(v0.z) << 16) |
      ((unsigned long long)f32_to_e4m3(v0.w) << 24) |
      ((unsigned long long)f32_to_e4m3(v1.x) << 32) |
      ((unsigned long long)f32_to_e4m3(v1.y) << 40) |
      ((unsigned long long)f32_to_e4m3(v1.z) << 48) |
      ((unsigned long long)f32_to_e4m3(v1.w) << 56);
  reinterpret_cast<unsigned long long*>(xq)[i] = w;
  if (i < NPTS) nn64[i] = 0ull;
}

__device__ __forceinline__ void gload_lds16(const unsigned char* g,
                                            unsigned char* l) {
  __builtin_amdgcn_global_load_lds(
      (__attribute__((address_space(1))) const void*)g,
      (__attribute__((address_space(3))) void*)l, 16, 0, 0);
}

__device__ __forceinline__ unsigned long long kmax(unsigned long long a,
                                                   unsigned long long b) {
  return a > b ? a : b;
}

// Triangular fused fp8 GEMM + dual argmax.
// grid = NBLK, block = 256 (4 waves, 2x2 grid of 64x64 sub-tiles).
// LDS: 3 buffers x (A 8KB + B 8KB) = 48 KB -> 3 blocks/CU.
__global__ __launch_bounds__(256, 3) void tri_gemm_kernel(
    const unsigned char* __restrict__ xq,
    unsigned long long* __restrict__ nn64) {
  __shared__ unsigned char lds[3][16384];

  // XCD-bijective swizzle (2080 = 8*260), then b -> (ti >= tj).
  const int orig = (int)blockIdx.x;
  int b = (orig & 7) * (NBLK >> 3) + (orig >> 3);
  int ti = (int)((sqrtf(8.0f * (float)b + 1.0f) - 1.0f) * 0.5f);
  while ((ti + 1) * (ti + 2) / 2 <= b) ++ti;
  while (ti * (ti + 1) / 2 > b) --ti;
  const int tj = b - ti * (ti + 1) / 2;

  const int tid  = (int)threadIdx.x;
  const int wid  = tid >> 6;
  const int lane = tid & 63;
  const int wr   = wid >> 1;      // 0..1
  const int wc   = wid & 1;       // 0..1
  const int l15  = lane & 15;
  const int l16  = lane >> 4;     // 0..3 (8-byte k-chunk index)
  const int arow0 = ti * BM;
  const int bcol0 = tj * BN;

  // Staging: row = 64 B = 4 slots of 16 B. LDS slot s of row r holds global
  // 16B chunk (s - ((r>>1)&3)) & 3  (rotation; involution inverse on read).
  // Thread t handles chunks t and t+256 of A, same of B.
#define STAGE(bufi, kt) do {                                                 \
    _Pragma("unroll")                                                        \
    for (int i_ = 0; i_ < 2; ++i_) {                                         \
      const int chunk_ = (i_ << 8) + tid;          /* 0..511 */              \
      const int row_   = chunk_ >> 2;              /* 0..127 */              \
      const int c_     = ((chunk_ & 3) - ((row_ >> 1) & 3)) & 3;             \
      gload_lds16(xq + (size_t)(arow0 + row_) * DIM + (kt) * 64 + (c_ << 4), \
                  &lds[bufi][chunk_ << 4]);                                   \
      gload_lds16(xq + (size_t)(bcol0 + row_) * DIM + (kt) * 64 + (c_ << 4), \
                  &lds[bufi][8192 + (chunk_ << 4)]);                          \
    }                                                                        \
  } while (0)

  // Fragment reads: lane (row r = band + l15, k-chunk l16) reads the b128
  // slot (l16 + rot) & 3 where rot = (r>>1)&3 = (l15>>1)&3 (bands are x16).
  const int rot = (l15 >> 1) & 3;
  int aoff[4], boff[4];
#pragma unroll
  for (int mi = 0; mi < 4; ++mi)
    aoff[mi] = (wr * 64 + mi * 16 + l15) * 64 + (((l16 + rot) & 3) << 4);
#pragma unroll
  for (int ni = 0; ni < 4; ++ni)
    boff[ni] = 8192 + (wc * 64 + ni * 16 + l15) * 64 + (((l16 + rot) & 3) << 4);

  f32x4 acc[4][4];
#pragma unroll
  for (int mi = 0; mi < 4; ++mi)
#pragma unroll
    for (int ni = 0; ni < 4; ++ni)
      acc[mi][ni] = (f32x4){0.f, 0.f, 0.f, 0.f};

  // Prologue: 2 K-tiles in flight (depth-2).
  STAGE(0, 0);
  STAGE(1, 1);

  int cur = 0, bs = 2;
  for (int u = 0; u < KT_N; ++u) {
    if (u + 2 < KT_N) {
      STAGE(bs, u + 2);
      asm volatile("s_waitcnt vmcnt(8)" ::: "memory");  // tile u's 4 done
    } else if (u + 2 == KT_N) {
      asm volatile("s_waitcnt vmcnt(4)" ::: "memory");
    } else {
      asm volatile("s_waitcnt vmcnt(0)" ::: "memory");
    }
    asm volatile("s_barrier" ::: "memory");             // buf[cur] published

    lx2 a2[4], b2[4];
#pragma unroll
    for (int mi = 0; mi < 4; ++mi)
      a2[mi] = *reinterpret_cast<const lx2*>(&lds[cur][aoff[mi]]);
#pragma unroll
    for (int ni = 0; ni < 4; ++ni)
      b2[ni] = *reinterpret_cast<const lx2*>(&lds[cur][boff[ni]]);
    __builtin_amdgcn_s_setprio(1);
#pragma unroll
    for (int mi = 0; mi < 4; ++mi)
#pragma unroll
      for (int ni = 0; ni < 4; ++ni) {
        acc[mi][ni] = __builtin_amdgcn_mfma_f32_16x16x32_fp8_fp8(
            a2[mi][0], b2[ni][0], acc[mi][ni], 0, 0, 0);
        acc[mi][ni] = __builtin_amdgcn_mfma_f32_16x16x32_fp8_fp8(
            a2[mi][1], b2[ni][1], acc[mi][ni], 0, 0, 0);
      }
    __builtin_amdgcn_s_setprio(0);

    asm volatile("s_barrier" ::: "memory");   // reads of buf[cur] done
    cur = (cur + 1 == 3) ? 0 : cur + 1;
    bs  = (bs  + 1 == 3) ? 0 : bs  + 1;
  }
#undef STAGE

  // ---- Epilogue: dual argmax. C/D layout: col=lane&15, row=(lane>>4)*4+reg.
  // Key = mono(v)<<32 | ~idx  (atomicMax => exact first-occurrence ties).

  // Row side: per output row, max over this wave's 64 columns.
#pragma unroll
  for (int mi = 0; mi < 4; ++mi)
#pragma unroll
    for (int j = 0; j < 4; ++j) {
      const int gi = arow0 + wr * 64 + mi * 16 + l16 * 4 + j;
      unsigned long long key = 0ull;
#pragma unroll
      for (int ni = 0; ni < 4; ++ni) {
        const int gj = bcol0 + wc * 64 + ni * 16 + l15;
        if (gi != gj) {
          unsigned long long k =
              ((unsigned long long)mono_f32(acc[mi][ni][j]) << 32) |
              (unsigned int)(~gj);
          key = kmax(key, k);
        }
      }
#pragma unroll
      for (int m = 1; m < 16; m <<= 1)
        key = kmax(key, __shfl_xor(key, m));
      if (l15 == 0) atomicMax(&nn64[gi], key);
    }

  // Col side (symmetry): per output col, max over this wave's 64 rows.
#pragma unroll
  for (int ni = 0; ni < 4; ++ni) {
    const int gj = bcol0 + wc * 64 + ni * 16 + l15;
    unsigned long long key = 0ull;
#pragma unroll
    for (int mi = 0; mi < 4; ++mi)
#pragma unroll
      for (int j = 0; j < 4; ++j) {
        const int gi = arow0 + wr * 64 + mi * 16 + l16 * 4 + j;
        if (gi != gj) {
          unsigned long long k =
              ((unsigned long long)mono_f32(acc[mi][ni][j]) << 32) |
              (unsigned int)(~gi);
          key = kmax(key, k);
        }
      }
#pragma unroll
    for (int m = 16; m < 64; m <<= 1)
      key = kmax(key, __shfl_xor(key, m));
    if (l16 == 0) atomicMax(&nn64[gj], key);
  }
}

// rho_r = ||x_r - x_{nn(r)} + 1e-6||_2 ; logs[r] = log(rho + 1e-8).
__global__ void dist_log_kernel(const float* __restrict__ x,
                                const unsigned long long* __restrict__ nn64,
                                float* __restrict__ logs) {
  const int row  = blockIdx.x * 4 + ((int)threadIdx.x >> 6);
  const int lane = (int)threadIdx.x & 63;
  const int nn   = (int)(~(unsigned int)(nn64[row] & 0xFFFFFFFFull)) & (NPTS - 1);
  const float4* xr = reinterpret_cast<const float4*>(x + (size_t)row * DIM);
  const float4* xn = reinterpret_cast<const float4*>(x + (size_t)nn  * DIM);
  float s = 0.f;
#pragma unroll
  for (int i = 0; i < 2; ++i) {
    float4 a = xr[lane + i * 64];
    float4 b = xn[lane + i * 64];
    float d0 = a.x - b.x + 1e-6f;
    float d1 = a.y - b.y + 1e-6f;
    float d2 = a.z - b.z + 1e-6f;
    float d3 = a.w - b.w + 1e-6f;
    s += d0 * d0 + d1 * d1 + d2 * d2 + d3 * d3;
  }
#pragma unroll
  for (int m = 32; m >= 1; m >>= 1) s += __shfl_xor(s, m);
  if (lane == 0) logs[row] = logf(sqrtf(s) + 1e-8f);
}

// Deterministic mean: 1024 threads x 8 sequential adds + LDS tree.
__global__ void final_reduce_kernel(const float* __restrict__ logs,
                                    float* __restrict__ out) {
  __shared__ float sm[1024];
  const int t = (int)threadIdx.x;
  float s = 0.f;
#pragma unroll
  for (int i = 0; i < 8; ++i) s += logs[t * 8 + i];
  sm[t] = s;
  __syncthreads();
  for (int k = 512; k > 0; k >>= 1) {
    if (t < k) sm[t] += sm[t + k];
    __syncthreads();
  }
  if (t == 0) out[0] = -(sm[0] / (float)NPTS);
}

extern "C" void kernel_launch(void* const* d_in, const int* in_sizes, int n_in,
                              void* d_out, int out_size, void* d_ws, size_t ws_size,
                              hipStream_t stream) {
  const float* x = (const float*)d_in[0];
  float* out = (float*)d_out;
  char* ws = (char*)d_ws;

  // Workspace layout (bytes):
  unsigned char*      xq   = (unsigned char*)(ws);                // 4 MB
  unsigned long long* nn64 = (unsigned long long*)(ws + 4194304); // 64 KB
  float*              logs = (float*)(ws + 4259840);              // 32 KB

  cvt_fp8_kernel<<<(NPTS * DIM / 8) / 256, 256, 0, stream>>>(x, xq, nn64);

  tri_gemm_kernel<<<NBLK, 256, 0, stream>>>(xq, nn64);

  dist_log_kernel<<<NPTS / 4, 256, 0, stream>>>(x, nn64, logs);

  final_reduce_kernel<<<1, 1024, 0, stream>>>(logs, out);
}